// Round 13
// baseline (124.877 us; speedup 1.0000x reference)
//
#include <hip/hip_runtime.h>
#include <math.h>

#define A_TOT   18675      // 83*25*9
#define N_PRE   12000
#define N_POST  2000
#define IMG_X   1333.0f
#define IMG_Y   402.0f
#define MIN_SZ  16.0f
#define NMS_T   0.7f
#define NBUCK   4096       // top 12 bits of descending-order key
#define NB0     19         // decode blocks (19*1024 >= A_TOT)
#define NB1     256        // main kernel blocks (1 block/CU -> co-resident)
#define NW1     (NB1*16)   // main kernel waves (4096)

// ---------------- D0: init + decode -> roi, key, partial hists ---------------
__global__ __launch_bounds__(1024)
void decode_kernel(const float* __restrict__ anch,
                   const float* __restrict__ cls,
                   const float* __restrict__ pred,
                   float4* __restrict__ roi,
                   unsigned long long* __restrict__ key,
                   unsigned* __restrict__ phist,
                   unsigned* __restrict__ gcnt,
                   unsigned* __restrict__ sync) {
    __shared__ unsigned lh[NBUCK];
    const int t   = threadIdx.x;
    const int blk = blockIdx.x;
    const int g   = blk * 1024 + t;

#pragma unroll
    for (int e = 0; e < 4; ++e) lh[t + e * 1024] = 0u;
    if (g < NBUCK) gcnt[g] = 0u;
    if (g == NBUCK) { sync[0] = 0u; sync[32] = 0u; }   // bar, done
    __syncthreads();

    if (g < A_TOT) {
        float ax1 = anch[4*g+0], ay1 = anch[4*g+1], ax2 = anch[4*g+2], ay2 = anch[4*g+3];
        float h_a  = __fsub_rn(ay2, ay1);
        float w_a  = __fsub_rn(ax2, ax1);
        float cy_a = __fadd_rn(ay1, __fmul_rn(0.5f, h_a));
        float cx_a = __fadd_rn(ax1, __fmul_rn(0.5f, w_a));

        float dx = pred[4*g+0], dy = pred[4*g+1], dw = pred[4*g+2], dh = pred[4*g+3];

        float cy = __fadd_rn(__fmul_rn(dy, h_a), cy_a);
        float cx = __fadd_rn(__fmul_rn(dx, w_a), cx_a);
        float h  = __fmul_rn(expf(dh), h_a);
        float w  = __fmul_rn(expf(dw), w_a);

        float hw = __fmul_rn(0.5f, w);
        float hh = __fmul_rn(0.5f, h);
        float x1 = fminf(fmaxf(__fsub_rn(cx, hw), 0.0f), IMG_X);
        float x2 = fminf(fmaxf(__fadd_rn(cx, hw), 0.0f), IMG_X);
        float y1 = fminf(fmaxf(__fsub_rn(cy, hh), 0.0f), IMG_Y);
        float y2 = fminf(fmaxf(__fadd_rn(cy, hh), 0.0f), IMG_Y);

        bool valid = (__fsub_rn(y2, y1) >= MIN_SZ) && (__fsub_rn(x2, x1) >= MIN_SZ);

        roi[g] = make_float4(x1, y1, x2, y2);

        float s = valid ? cls[2*g+1] : -INFINITY;
        unsigned ub   = __float_as_uint(s);
        unsigned mask = ((unsigned)((int)ub >> 31)) | 0x80000000u;
        unsigned ord  = ub ^ mask;          // ascending float order
        unsigned kd   = ~ord;               // descending float order
        key[g] = ((unsigned long long)kd << 32) | (unsigned)g;
        atomicAdd(&lh[kd >> 20], 1u);
    }
    __syncthreads();

    ((uint4*)phist)[blk * 1024 + t] =
        make_uint4(lh[4*t+0], lh[4*t+1], lh[4*t+2], lh[4*t+3]);
}

// -------- hand-rolled grid barrier: RMW arrive, LOAD poll --------------------
__device__ __forceinline__ void gbar(unsigned* bar, unsigned target) {
    __syncthreads();
    if (threadIdx.x == 0) {
        __threadfence();                 // release prior writes to device scope
        __hip_atomic_fetch_add(bar, 1u, __ATOMIC_RELEASE, __HIP_MEMORY_SCOPE_AGENT);
        long guard = 0;
        while (__hip_atomic_load(bar, __ATOMIC_ACQUIRE, __HIP_MEMORY_SCOPE_AGENT) < target) {
            __builtin_amdgcn_s_sleep(2);
            if (++guard > (1L << 24)) break;   // hang guard only
        }
        __threadfence();                 // acquire
    }
    __syncthreads();
}

__device__ __forceinline__ float box_area(float4 b) {
    return __fmul_rn(__fadd_rn(__fsub_rn(b.z, b.x), 1.0f),
                     __fadd_rn(__fsub_rn(b.w, b.y), 1.0f));
}

// IoU >= NMS_T, op-order identical to reference: inter / ((az + ao) - inter)
__device__ __forceinline__ bool iou_over(float4 cz, float az, float4 co) {
    float xx1 = fmaxf(cz.x, co.x);
    float yy1 = fmaxf(cz.y, co.y);
    float xx2 = fminf(cz.z, co.z);
    float yy2 = fminf(cz.w, co.w);
    float w = fmaxf(0.0f, __fadd_rn(__fsub_rn(xx2, xx1), 1.0f));
    float h = fmaxf(0.0f, __fadd_rn(__fsub_rn(yy2, yy1), 1.0f));
    float inter = __fmul_rn(w, h);
    float ao = box_area(co);
    float denom = __fsub_rn(__fadd_rn(az, ao), inter);
    return __fdiv_rn(inter, denom) >= NMS_T;
}

// ---------------- D1: scan+scatter | rank | nms | last-block output ----------
__global__ __launch_bounds__(1024)
void main_kernel(const unsigned long long* __restrict__ key,
                 const unsigned* __restrict__ phist,
                 unsigned* __restrict__ gcnt,
                 unsigned long long* __restrict__ bkey,
                 const float4* __restrict__ roi,
                 float4* __restrict__ sboxes,
                 unsigned* __restrict__ mark,
                 unsigned* __restrict__ sync,
                 float* __restrict__ out) {
    __shared__ unsigned bs[NBUCK];
    __shared__ unsigned lcnt[NBUCK];
    __shared__ unsigned wsum[16];
    __shared__ int osum[16];
    __shared__ int ototal;
    __shared__ int sflag;

    const int t    = threadIdx.x;
    const int blk  = blockIdx.x;
    const int lane = t & 63;
    const int wv   = t >> 6;
    const int gw   = blk * 16 + wv;

    // ----- phase A: redundant per-block exclusive scan of summed hists -----
    {
        unsigned c0 = 0, c1 = 0, c2 = 0, c3 = 0;
#pragma unroll
        for (int k = 0; k < NB0; ++k) {
            uint4 v = ((const uint4*)phist)[k * 1024 + t];
            c0 += v.x; c1 += v.y; c2 += v.z; c3 += v.w;
        }
        unsigned mysum = c0 + c1 + c2 + c3;
        unsigned incl = mysum;
#pragma unroll
        for (int off = 1; off < 64; off <<= 1) {
            unsigned x = __shfl_up(incl, off, 64);
            if (lane >= off) incl += x;
        }
        if (lane == 63) wsum[wv] = incl;
        __syncthreads();
        if (t == 0) {
            unsigned run = 0;
            for (int k = 0; k < 16; ++k) { unsigned x = wsum[k]; wsum[k] = run; run += x; }
        }
        __syncthreads();
        unsigned base = wsum[wv] + (incl - mysum);
        bs[4*t+0] = base;
        bs[4*t+1] = base + c0;
        bs[4*t+2] = base + c0 + c1;
        bs[4*t+3] = base + c0 + c1 + c2;
        lcnt[4*t+0] = c0; lcnt[4*t+1] = c1; lcnt[4*t+2] = c2; lcnt[4*t+3] = c3;
        __syncthreads();
    }

    // ----- phase B: bucket scatter (blocks 0..18 carry the elements) -----
    {
        int g = blk * 1024 + t;
        if (g < A_TOT) {
            unsigned long long Ki = key[g];
            unsigned b = (unsigned)(Ki >> 52);
            unsigned pos = bs[b] + atomicAdd(&gcnt[b], 1u);
            bkey[pos] = Ki;
        }
    }
    gbar(sync, NB1);

    // ----- phase C: wave-ballot exact rank + scatter to sorted boxes -----
    for (int p = gw; p < A_TOT; p += NW1) {
        unsigned long long Ki = bkey[p];
        unsigned b = (unsigned)(Ki >> 52);
        unsigned start = bs[b];
        if (start >= N_PRE) continue;        // whole bucket past top-N_PRE
        unsigned cnt = lcnt[b];
        unsigned r = start;
        if (cnt > 1) {
            for (unsigned m = 0; m < cnt; m += 64) {
                unsigned mm = m + lane;
                bool lt = (mm < cnt) && (bkey[start + mm] < Ki);
                r += (unsigned)__popcll(__ballot(lt));
            }
        }
        if (lane == 0 && r < N_PRE) {
            sboxes[r] = roi[(unsigned)Ki];
        }
    }
    gbar(sync, 2u * NB1);

    // ----- phase D: diagonal marking, 3 balanced streams/wave, 2-deep prefetch
    // mark[i] = OR over z in [0, N_PRE-1-i) of IoU(b[z], b[z+i+1]) >= 0.7
    {
        const int w  = gw;                         // 0..4095
        const int i0 = w;                          // long diagonal
        const int i1 = 8191 - w;                   // medium
        const int i2 = (w < N_PRE - 8192) ? (8192 + w) : -1;   // short
        const int np0 = N_PRE - 1 - i0;
        const int np1 = N_PRE - 1 - i1;
        const int np2 = (i2 >= 0) ? (N_PRE - 1 - i2) : 0;
        bool f0 = false, f1 = false, f2 = (i2 < 0);
        const int maxr = (np0 + 63) >> 6;          // np0 is the largest

        int z0 = lane;
        float4 cz  = sboxes[z0 < N_PRE ? z0 : 0];
        float4 co0 = sboxes[min(z0 + i0 + 1, N_PRE - 1)];
        float4 co1 = sboxes[min(z0 + i1 + 1, N_PRE - 1)];
        float4 co2 = (i2 >= 0) ? sboxes[min(z0 + i2 + 1, N_PRE - 1)] : cz;

        for (int rr = 0; rr < maxr; ++rr) {
            const int zb = rr << 6;
            const bool a0 = !f0 && zb < np0;
            const bool a1 = !f1 && zb < np1;
            const bool a2 = !f2 && zb < np2;
            if (!(a0 || a1 || a2)) break;

            float4 ccz = cz, cc0 = co0, cc1 = co1, cc2 = co2;
            // prefetch next round (finished streams read line 0 - broadcast, ~free)
            int zn = zb + 64 + lane;
            cz  = sboxes[zn < N_PRE ? zn : 0];
            co0 = sboxes[a0 ? min(zn + i0 + 1, N_PRE - 1) : 0];
            co1 = sboxes[a1 ? min(zn + i1 + 1, N_PRE - 1) : 0];
            co2 = sboxes[a2 ? min(zn + i2 + 1, N_PRE - 1) : 0];

            const int zz = zb + lane;
            const float az = box_area(ccz);
            if (a0) {
                bool over = (zz < np0) && iou_over(ccz, az, cc0);
                if (__any(over)) f0 = true;
            }
            if (a1) {
                bool over = (zz < np1) && iou_over(ccz, az, cc1);
                if (__any(over)) f1 = true;
            }
            if (a2) {
                bool over = (zz < np2) && iou_over(ccz, az, cc2);
                if (__any(over)) f2 = true;
            }
        }
        if (lane == 0) {
            mark[i0] = f0 ? 1u : 0u;
            mark[i1] = f1 ? 1u : 0u;
            if (i2 >= 0) mark[i2] = f2 ? 1u : 0u;
        }
    }

    // ----- phase E: last block to finish performs the output -----
    __syncthreads();
    if (t == 0) {
        __threadfence();
        unsigned old = atomicAdd(&sync[32], 1u);
        sflag = (old == NB1 - 1) ? 1 : 0;
    }
    __syncthreads();
    if (!sflag) return;
    __threadfence();

    {
        const int E = 12;                 // 1024*12 = 12288 >= 12000
        const int i0 = t * E;
        bool keep[E];
        int cnt = 0;
#pragma unroll
        for (int e = 0; e < E; ++e) {
            int i = i0 + e;
            bool k = (i < N_PRE) && (mark[i] == 0u);
            keep[e] = k;
            cnt += k ? 1 : 0;
        }
        int incl = cnt;
#pragma unroll
        for (int off = 1; off < 64; off <<= 1) {
            int x = __shfl_up(incl, off, 64);
            if (lane >= off) incl += x;
        }
        if (lane == 63) osum[wv] = incl;
        __syncthreads();
        if (t == 0) {
            int run = 0;
            for (int k = 0; k < 16; ++k) { int x = osum[k]; osum[k] = run; run += x; }
            ototal = run;
        }
        __syncthreads();

        int pos = osum[wv] + (incl - cnt);
#pragma unroll
        for (int e = 0; e < E; ++e) {
            if (keep[e] && pos < N_POST) {
                float4 b4 = sboxes[i0 + e];
                out[4*pos+0] = b4.x;
                out[4*pos+1] = b4.y;
                out[4*pos+2] = b4.z;
                out[4*pos+3] = b4.w;
                out[4*N_POST + pos] = 1.0f;
            }
            pos += keep[e] ? 1 : 0;
        }
        const int total = ototal;
        for (int p = t; p < N_POST; p += 1024) {
            if (p >= total) {
                out[4*p+0] = 0.0f; out[4*p+1] = 0.0f;
                out[4*p+2] = 0.0f; out[4*p+3] = 0.0f;
                out[4*N_POST + p] = 0.0f;
            }
        }
    }
}

// ---------------- launch ------------------------------------------------------
extern "C" void kernel_launch(void* const* d_in, const int* in_sizes, int n_in,
                              void* d_out, int out_size, void* d_ws, size_t ws_size,
                              hipStream_t stream) {
    const float* anch = (const float*)d_in[0];   // (A,4)
    const float* cls  = (const float*)d_in[1];   // (1,A,2)
    const float* pred = (const float*)d_in[2];   // (1,A,4)
    float* out = (float*)d_out;                  // 8000 rois + 2000 kept

    char* ws = (char*)d_ws;
    float4*             roi    = (float4*)(ws + 0);                   // 298,800
    unsigned long long* key    = (unsigned long long*)(ws + 299008);  // 149,400
    unsigned*           phist  = (unsigned*)(ws + 448512);            // 311,296 (19*16KB)
    unsigned*           gcnt   = (unsigned*)(ws + 759808);            //  16,384
    unsigned long long* bkey   = (unsigned long long*)(ws + 776192);  // 149,400
    float4*             sboxes = (float4*)(ws + 925696);              // 192,000
    unsigned*           mark   = (unsigned*)(ws + 1117696);           //  48,000
    unsigned*           sync   = (unsigned*)(ws + 1165696);           //     256

    decode_kernel<<<NB0, 1024, 0, stream>>>(anch, cls, pred, roi, key, phist, gcnt, sync);
    main_kernel<<<NB1, 1024, 0, stream>>>(key, phist, gcnt, bkey, roi,
                                          sboxes, mark, sync, out);
}

// Round 14
// 51.818 us; speedup vs baseline: 2.4099x; 2.4099x over previous
//
#include <hip/hip_runtime.h>
#include <math.h>

#define A_TOT   18675      // 83*25*9
#define N_PRE   12000
#define N_POST  2000
#define IMG_X   1333.0f
#define IMG_Y   402.0f
#define MIN_SZ  16.0f
#define NMS_T   0.7f
#define NBUCK   4096       // top 12 bits of descending-order key

// ---------------- K1: decode -> roi, key64 -----------------------------------
__global__ void decode_kernel(const float* __restrict__ anch,
                              const float* __restrict__ cls,
                              const float* __restrict__ pred,
                              float4* __restrict__ roi,
                              unsigned long long* __restrict__ key) {
    int i = blockIdx.x * blockDim.x + threadIdx.x;
    if (i >= A_TOT) return;

    float ax1 = anch[4*i+0], ay1 = anch[4*i+1], ax2 = anch[4*i+2], ay2 = anch[4*i+3];
    float h_a  = __fsub_rn(ay2, ay1);
    float w_a  = __fsub_rn(ax2, ax1);
    float cy_a = __fadd_rn(ay1, __fmul_rn(0.5f, h_a));
    float cx_a = __fadd_rn(ax1, __fmul_rn(0.5f, w_a));

    float dx = pred[4*i+0], dy = pred[4*i+1], dw = pred[4*i+2], dh = pred[4*i+3];

    float cy = __fadd_rn(__fmul_rn(dy, h_a), cy_a);
    float cx = __fadd_rn(__fmul_rn(dx, w_a), cx_a);
    float h  = __fmul_rn(expf(dh), h_a);
    float w  = __fmul_rn(expf(dw), w_a);

    float hw = __fmul_rn(0.5f, w);
    float hh = __fmul_rn(0.5f, h);
    float x1 = fminf(fmaxf(__fsub_rn(cx, hw), 0.0f), IMG_X);
    float x2 = fminf(fmaxf(__fadd_rn(cx, hw), 0.0f), IMG_X);
    float y1 = fminf(fmaxf(__fsub_rn(cy, hh), 0.0f), IMG_Y);
    float y2 = fminf(fmaxf(__fadd_rn(cy, hh), 0.0f), IMG_Y);

    bool valid = (__fsub_rn(y2, y1) >= MIN_SZ) && (__fsub_rn(x2, x1) >= MIN_SZ);

    roi[i] = make_float4(x1, y1, x2, y2);

    float s = valid ? cls[2*i+1] : -INFINITY;
    // strictly-unique 64-bit key: ascending K == (descending score, ascending index)
    unsigned ub   = __float_as_uint(s);
    unsigned mask = ((unsigned)((int)ub >> 31)) | 0x80000000u;
    unsigned ord  = ub ^ mask;          // ascending float order
    unsigned kd   = ~ord;               // descending float order
    key[i] = ((unsigned long long)kd << 32) | (unsigned)i;
}

// ---------------- K2: fused hist + scan + bucket scatter (1 block) -----------
__global__ __launch_bounds__(1024)
void sortprep_kernel(const unsigned long long* __restrict__ key,
                     unsigned long long* __restrict__ bkey,
                     unsigned* __restrict__ bstart,
                     unsigned* __restrict__ bcnt) {
    __shared__ unsigned cur[NBUCK];   // histogram -> cursor
    __shared__ unsigned wsum[16];
    const int t    = threadIdx.x;     // 0..1023
    const int lane = t & 63;
    const int wv   = t >> 6;          // 0..15

#pragma unroll
    for (int e = 0; e < 4; ++e) cur[t + e * 1024] = 0u;
    __syncthreads();

    for (int j = t; j < A_TOT; j += 1024)
        atomicAdd(&cur[(unsigned)(key[j] >> 52)], 1u);
    __syncthreads();

    // each thread owns buckets [4t, 4t+4)
    unsigned c0 = cur[4*t+0], c1 = cur[4*t+1], c2 = cur[4*t+2], c3 = cur[4*t+3];
    unsigned mysum = c0 + c1 + c2 + c3;

    unsigned incl = mysum;
#pragma unroll
    for (int off = 1; off < 64; off <<= 1) {
        unsigned v = __shfl_up(incl, off, 64);
        if (lane >= off) incl += v;
    }
    if (lane == 63) wsum[wv] = incl;
    __syncthreads();
    if (t == 0) {
        unsigned run = 0;
        for (int k = 0; k < 16; ++k) { unsigned v = wsum[k]; wsum[k] = run; run += v; }
    }
    __syncthreads();

    unsigned base = wsum[wv] + (incl - mysum);   // exclusive prefix of bucket 4t
    unsigned s0 = base, s1 = s0 + c0, s2 = s1 + c1, s3 = s2 + c2;

    ((uint4*)bstart)[t] = make_uint4(s0, s1, s2, s3);
    ((uint4*)bcnt)[t]   = make_uint4(c0, c1, c2, c3);

    cur[4*t+0] = s0; cur[4*t+1] = s1; cur[4*t+2] = s2; cur[4*t+3] = s3;
    __syncthreads();

    for (int j = t; j < A_TOT; j += 1024) {
        unsigned long long Ki = key[j];
        unsigned pos = atomicAdd(&cur[(unsigned)(Ki >> 52)], 1u);
        bkey[pos] = Ki;
    }
}

// ---------------- K3: wave-cooperative exact rank + scatter ------------------
__global__ void rankscatter_kernel(const unsigned long long* __restrict__ bkey,
                                   const unsigned* __restrict__ bstart,
                                   const unsigned* __restrict__ bcnt,
                                   const float4* __restrict__ roi,
                                   float4* __restrict__ sboxes) {
    int g = blockIdx.x * blockDim.x + threadIdx.x;
    int p = g >> 6;
    int lane = g & 63;
    if (p >= A_TOT) return;

    unsigned long long Ki = bkey[p];
    unsigned b = (unsigned)(Ki >> 52);
    unsigned start = bstart[b];
    if (start >= N_PRE) return;          // whole bucket past top-N_PRE
    unsigned cnt = bcnt[b];

    unsigned r = start;
    for (unsigned m = 0; m < cnt; m += 64) {
        unsigned mm = m + lane;
        bool lt = (mm < cnt) && (bkey[start + mm] < Ki);
        r += (unsigned)__popcll(__ballot(lt));
    }

    if (lane == 0 && r < N_PRE) {
        sboxes[r] = roi[(unsigned)Ki];
    }
}

__device__ __forceinline__ float box_area(float4 b) {
    return __fmul_rn(__fadd_rn(__fsub_rn(b.z, b.x), 1.0f),
                     __fadd_rn(__fsub_rn(b.w, b.y), 1.0f));
}

// ---------------- K4: diagonal pair-overlap marking --------------------------
// mark[i] = OR over z in [0, N_PRE-1-i) of IoU(b[z], b[z+i+1]) >= 0.7
// One wave per i; areas recomputed in-register (bit-identical to reference);
// 1-deep software prefetch hides the per-round load latency on the serial tail.
__global__ void nms_kernel(const float4* __restrict__ sboxes,
                           unsigned* __restrict__ mark) {
    int wid  = (blockIdx.x * blockDim.x + threadIdx.x) >> 6;
    int lane = threadIdx.x & 63;
    if (wid >= N_PRE) return;
    const int i      = wid;
    const int npairs = N_PRE - 1 - i;   // z in [0, npairs)
    const int rounds = (npairs + 63) >> 6;

    bool found = false;
    if (rounds > 0) {
        float4 bz = sboxes[min(lane, npairs - 1)];
        float4 bo = sboxes[min(lane + i + 1, N_PRE - 1)];
        for (int rr = 0; rr < rounds; ++rr) {
            float4 cz = bz, co = bo;
            if (rr + 1 < rounds) {                 // prefetch next round
                int zn = ((rr + 1) << 6) + lane;
                bz = sboxes[min(zn, npairs - 1)];
                bo = sboxes[min(zn + i + 1, N_PRE - 1)];
            }
            int z = (rr << 6) + lane;
            bool over = false;
            if (z < npairs) {
                float xx1 = fmaxf(cz.x, co.x);
                float yy1 = fmaxf(cz.y, co.y);
                float xx2 = fminf(cz.z, co.z);
                float yy2 = fminf(cz.w, co.w);
                float w = fmaxf(0.0f, __fadd_rn(__fsub_rn(xx2, xx1), 1.0f));
                float h = fmaxf(0.0f, __fadd_rn(__fsub_rn(yy2, yy1), 1.0f));
                float inter = __fmul_rn(w, h);
                float az = box_area(cz);
                float ao = box_area(co);
                float denom = __fsub_rn(__fadd_rn(az, ao), inter);
                float ovr   = __fdiv_rn(inter, denom);
                over = (ovr >= NMS_T);
            }
            if (__any(over)) { found = true; break; }
        }
    }
    if (lane == 0) mark[i] = found ? 1u : 0u;
}

// ---------------- K5: stable compaction + output (shfl scan) -----------------
__global__ __launch_bounds__(1024)
void output_kernel(const unsigned* __restrict__ mark,
                   const float4* __restrict__ sboxes,
                   float* __restrict__ out) {
    __shared__ int wsum[16];
    __shared__ int s_total;
    const int t    = threadIdx.x;     // 0..1023
    const int lane = t & 63;
    const int wv   = t >> 6;
    const int E = 12;                 // 1024*12 = 12288 >= 12000
    const int i0 = t * E;

    bool keep[E];
    int cnt = 0;
#pragma unroll
    for (int e = 0; e < E; ++e) {
        int i = i0 + e;
        bool k = (i < N_PRE) && (mark[i] == 0u);
        keep[e] = k;
        cnt += k ? 1 : 0;
    }

    int incl = cnt;
#pragma unroll
    for (int off = 1; off < 64; off <<= 1) {
        int v = __shfl_up(incl, off, 64);
        if (lane >= off) incl += v;
    }
    if (lane == 63) wsum[wv] = incl;
    __syncthreads();
    if (t == 0) {
        int run = 0;
        for (int k = 0; k < 16; ++k) { int v = wsum[k]; wsum[k] = run; run += v; }
        s_total = run;
    }
    __syncthreads();

    int base = wsum[wv] + (incl - cnt);
    const int total = s_total;

    int pos = base;
#pragma unroll
    for (int e = 0; e < E; ++e) {
        if (keep[e] && pos < N_POST) {
            float4 b = sboxes[i0 + e];
            out[4*pos+0] = b.x;
            out[4*pos+1] = b.y;
            out[4*pos+2] = b.z;
            out[4*pos+3] = b.w;
            out[4*N_POST + pos] = 1.0f;
        }
        pos += keep[e] ? 1 : 0;
    }
    for (int p = t; p < N_POST; p += 1024) {
        if (p >= total) {
            out[4*p+0] = 0.0f; out[4*p+1] = 0.0f;
            out[4*p+2] = 0.0f; out[4*p+3] = 0.0f;
            out[4*N_POST + p] = 0.0f;
        }
    }
}

// ---------------- launch ------------------------------------------------------
extern "C" void kernel_launch(void* const* d_in, const int* in_sizes, int n_in,
                              void* d_out, int out_size, void* d_ws, size_t ws_size,
                              hipStream_t stream) {
    const float* anch = (const float*)d_in[0];   // (A,4)
    const float* cls  = (const float*)d_in[1];   // (1,A,2)
    const float* pred = (const float*)d_in[2];   // (1,A,4)
    float* out = (float*)d_out;                  // 8000 rois + 2000 kept

    char* ws = (char*)d_ws;
    float4*             roi    = (float4*)(ws + 0);                   // 298,800
    unsigned long long* key    = (unsigned long long*)(ws + 299008);  // 149,400
    unsigned long long* bkey   = (unsigned long long*)(ws + 448512);  // 149,400
    unsigned*           bstart = (unsigned*)(ws + 598016);            //  16,384
    unsigned*           bcnt   = (unsigned*)(ws + 614400);            //  16,384
    float4*             sboxes = (float4*)(ws + 630784);              // 192,000
    unsigned*           mark   = (unsigned*)(ws + 822784);            //  48,000

    const int TB = 256;
    const int ablk = (A_TOT + TB - 1) / TB;            // 73
    const int rblk = (A_TOT * 64 + TB - 1) / TB;       // 4669

    decode_kernel<<<ablk, TB, 0, stream>>>(anch, cls, pred, roi, key);
    sortprep_kernel<<<1, 1024, 0, stream>>>(key, bkey, bstart, bcnt);
    rankscatter_kernel<<<rblk, TB, 0, stream>>>(bkey, bstart, bcnt, roi, sboxes);
    nms_kernel<<<(N_PRE * 64) / TB, TB, 0, stream>>>(sboxes, mark);
    output_kernel<<<1, 1024, 0, stream>>>(mark, sboxes, out);
}